// Round 1
// baseline (229.785 us; speedup 1.0000x reference)
//
#include <hip/hip_runtime.h>

// SubManifold gather: out[b,w,i,j] = x[b, idx[w,i], idx[w,j]]
// idx[w=wr*10+wc, i=a*12+b] = 192*wr + 4*wc + 48*a + b
// Static config: D=48, N=2304, K=12 (kk=144), S=4, 10x10=100 windows, BS=8.
// Output: [8,100,144,144] fp32 = 16,588,800 elems.
// One thread per output float4: 4,147,200 float4 = 16200 blocks x 256 threads.

#ifndef __align__
#define __align__(x) __attribute__((aligned(x)))
#endif

namespace {
constexpr int NTOK = 2304;   // N = 48*48
constexpr int NW   = 100;    // windows
constexpr int KK   = 144;    // k*k
constexpr int QPR  = 36;     // float4 per output row (144/4)
constexpr int TOTAL_F4 = 8 * NW * KK * QPR;  // 4,147,200
}

__global__ __launch_bounds__(256) void submanifold_gather(
    const float* __restrict__ x, float4* __restrict__ out) {
    int t = blockIdx.x * 256 + threadIdx.x;   // exact grid, no bounds check

    int q   = t % QPR;          // which float4 within a 144-long out row
    int rid = t / QPR;          // (b, w, i)
    int i   = rid % KK;
    int bw  = rid / KK;
    int w   = bw % NW;
    int b   = bw / NW;

    int wr = w / 10;
    int wc = w - wr * 10;
    int base = 192 * wr + 4 * wc;          // window's flat token base

    int ai = i / 12;
    int bi = i - ai * 12;
    int r  = base + 48 * ai + bi;          // source row (flat token idx)

    int aj  = q / 3;
    int bj4 = (q - aj * 3) * 4;
    int c   = base + 48 * aj + bj4;        // source col start (mult of 4)

    const float4* src = reinterpret_cast<const float4*>(
        x + (size_t)b * NTOK * NTOK + (size_t)r * NTOK + c);
    out[t] = *src;
}

extern "C" void kernel_launch(void* const* d_in, const int* in_sizes, int n_in,
                              void* d_out, int out_size, void* d_ws, size_t ws_size,
                              hipStream_t stream) {
    const float* x = (const float*)d_in[0];
    float4* out = (float4*)d_out;
    const int blocks = TOTAL_F4 / 256;  // 16200, exact
    submanifold_gather<<<blocks, 256, 0, stream>>>(x, out);
}